// Round 14
// baseline (250.243 us; speedup 1.0000x reference)
//
#include <hip/hip_runtime.h>
#include <cstdint>

#define TT 4096
#define BB 256
#define ID 128

typedef float f32x4 __attribute__((ext_vector_type(4)));
typedef float f32x2 __attribute__((ext_vector_type(2)));
typedef short s16x8 __attribute__((ext_vector_type(8)));

__device__ __forceinline__ float rcp_fast(float x) { return __builtin_amdgcn_rcpf(x); }
__device__ __forceinline__ float sigm(float x) { return rcp_fast(1.0f + __expf(-x)); }
__device__ __forceinline__ float tanh_fast(float x) {
  float e = __expf(2.0f * x);          // large +x -> inf -> 1; large -x -> 0 -> -1
  return 1.0f - 2.0f * rcp_fast(e + 1.0f);
}

union U16B { uint32_t u[4]; s16x8 v; };

// Split 8 f32 (two f32x4) into bf16-hi (truncate) + bf16-lo (exact residual).
// x = hi + rest exactly up to rest's own 2^-16; 3-product GEMM error ~1e-4.
__device__ __forceinline__ void split8(const f32x4 a, const f32x4 b,
                                       s16x8& hi, s16x8& lo) {
  uint32_t a0 = __float_as_uint(a[0]), a1 = __float_as_uint(a[1]);
  uint32_t a2 = __float_as_uint(a[2]), a3 = __float_as_uint(a[3]);
  uint32_t b0 = __float_as_uint(b[0]), b1 = __float_as_uint(b[1]);
  uint32_t b2 = __float_as_uint(b[2]), b3 = __float_as_uint(b[3]);
  U16B h;
  h.u[0] = (a0 >> 16) | (a1 & 0xffff0000u);
  h.u[1] = (a2 >> 16) | (a3 & 0xffff0000u);
  h.u[2] = (b0 >> 16) | (b1 & 0xffff0000u);
  h.u[3] = (b2 >> 16) | (b3 & 0xffff0000u);
  hi = h.v;
  float r0 = a[0] - __uint_as_float(a0 & 0xffff0000u);
  float r1 = a[1] - __uint_as_float(a1 & 0xffff0000u);
  float r2 = a[2] - __uint_as_float(a2 & 0xffff0000u);
  float r3 = a[3] - __uint_as_float(a3 & 0xffff0000u);
  float r4 = b[0] - __uint_as_float(b0 & 0xffff0000u);
  float r5 = b[1] - __uint_as_float(b1 & 0xffff0000u);
  float r6 = b[2] - __uint_as_float(b2 & 0xffff0000u);
  float r7 = b[3] - __uint_as_float(b3 & 0xffff0000u);
  U16B l;
  l.u[0] = (__float_as_uint(r0) >> 16) | (__float_as_uint(r1) & 0xffff0000u);
  l.u[1] = (__float_as_uint(r2) >> 16) | (__float_as_uint(r3) & 0xffff0000u);
  l.u[2] = (__float_as_uint(r4) >> 16) | (__float_as_uint(r5) & 0xffff0000u);
  l.u[3] = (__float_as_uint(r6) >> 16) | (__float_as_uint(r7) & 0xffff0000u);
  lo = l.v;
}

// One-time prep (R4-verified): split-bf16 B fragments in FINAL fragment order.
// Permuted-B mapping: output col m holds gate gp = (m&3)*8 + (m>>2)
// (xg layout [row][j][comp], comp = i,f,g,o). bo[m] = b_ih[gp]+b_hh[gp].
__global__ __launch_bounds__(64) void prep_kernel(
    const float* __restrict__ W_ih, const float* __restrict__ b_ih,
    const float* __restrict__ b_hh,
    s16x8* __restrict__ whi, s16x8* __restrict__ wlo, float* __restrict__ bo)
{
  const int lane = threadIdx.x;              // 0..63
  const int kq   = (lane >> 4) * 2;
  const f32x4* __restrict__ w4 = reinterpret_cast<const f32x4*>(W_ih);
#pragma unroll
  for (int kc = 0; kc < 4; ++kc) {
#pragma unroll
    for (int nf = 0; nf < 2; ++nf) {
      int m  = nf * 16 + (lane & 15);
      int gp = (m & 3) * 8 + (m >> 2);
      int q0 = kc * 8 + kq;
      f32x4 wa = w4[gp * 32 + q0];
      f32x4 wb = w4[gp * 32 + q0 + 1];
      s16x8 hi, lo;
      split8(wa, wb, hi, lo);
      whi[(kc * 2 + nf) * 64 + lane] = hi;
      wlo[(kc * 2 + nf) * 64 + lane] = lo;
    }
  }
  if (lane < 32) {
    int gp = (lane & 3) * 8 + (lane >> 2);
    bo[lane] = b_ih[gp] + b_hh[gp];
  }
}

// gates via MFMA (R4/R8/R12-verified structure). ONLY change vs R12:
// nontemporal x staging loads + nontemporal xg stores (zero-reuse streams;
// keep them out of L2 allocation so the read and write streams don't thrash).
// W fragments (L2-hot, reused by all 16384 blocks) stay cached.
__global__ __launch_bounds__(256) void gates_kernel(
    const float* __restrict__ x,
    const s16x8* __restrict__ whi, const s16x8* __restrict__ wlo,
    const float* __restrict__ bo, float* __restrict__ xg)
{
  __shared__ f32x4 xt[64 * 32];   // 32 KB  [row][q ^ (row&31)]
  const int tid = threadIdx.x;
  const size_t row0 = (size_t)blockIdx.x * 64;

  const f32x4* __restrict__ src = reinterpret_cast<const f32x4*>(x) + row0 * 32;
#pragma unroll
  for (int it = 0; it < 8; ++it) {           // 2048 f4, coalesced, streaming
    int idx = it * 256 + tid;
    int r = idx >> 5, q = idx & 31;
    xt[r * 32 + (q ^ (r & 31))] = __builtin_nontemporal_load(&src[idx]);
  }

  const int lane = tid & 63;
  const int wv   = tid >> 6;
  const int rloc = wv * 16 + (lane & 15);    // A-frag row (local)
  const int kq   = (lane >> 4) * 2;          // quad offset of this lane's k-chunk

  s16x8 Bh[4][2], Bl[4][2];
#pragma unroll
  for (int kc = 0; kc < 4; ++kc) {
#pragma unroll
    for (int nf = 0; nf < 2; ++nf) {
      Bh[kc][nf] = whi[(kc * 2 + nf) * 64 + lane];
      Bl[kc][nf] = wlo[(kc * 2 + nf) * 64 + lane];
    }
  }
  const float bo0 = bo[lane & 15];
  const float bo1 = bo[16 + (lane & 15)];

  __syncthreads();

  f32x4 acc[2] = {{0.f, 0.f, 0.f, 0.f}, {0.f, 0.f, 0.f, 0.f}};
#pragma unroll
  for (int kc = 0; kc < 4; ++kc) {
    int q0 = kc * 8 + kq;
    f32x4 xa = xt[rloc * 32 + (q0 ^ (rloc & 31))];
    f32x4 xb = xt[rloc * 32 + ((q0 + 1) ^ (rloc & 31))];
    s16x8 Ah, Al;
    split8(xa, xb, Ah, Al);
#pragma unroll
    for (int nf = 0; nf < 2; ++nf) {
      acc[nf] = __builtin_amdgcn_mfma_f32_16x16x32_bf16(Ah, Bh[kc][nf], acc[nf], 0, 0, 0);
      acc[nf] = __builtin_amdgcn_mfma_f32_16x16x32_bf16(Ah, Bl[kc][nf], acc[nf], 0, 0, 0);
      acc[nf] = __builtin_amdgcn_mfma_f32_16x16x32_bf16(Al, Bh[kc][nf], acc[nf], 0, 0, 0);
    }
  }

  // C/D: col = lane&15, row = (lane>>4)*4 + reg  [m89-verified]
#pragma unroll
  for (int nf = 0; nf < 2; ++nf) {
    int m = nf * 16 + (lane & 15);
    float b = nf ? bo1 : bo0;
    size_t rowg = row0 + wv * 16 + (lane >> 4) * 4;
#pragma unroll
    for (int reg = 0; reg < 4; ++reg) {
      __builtin_nontemporal_store(acc[nf][reg] + b, &xg[(rowg + reg) * 32 + m]);
    }
  }
}

// rnn (R8/R12-verified scan). ONLY change vs R12: nontemporal xg loads
// and nontemporal hout/vout stores (all zero-reuse streams).
__global__ __launch_bounds__(64) void rnn_kernel(
    const float* __restrict__ xg, const int* __restrict__ reset_idx,
    const float* __restrict__ W_hh, const float* __restrict__ W_proj,
    const float* __restrict__ b_proj, float* __restrict__ out)
{
  const int seg  = blockIdx.x;          // 0..32
  const int lane = threadIdx.x;
  const int j    = lane & 7;
  const int b    = blockIdx.y * 8 + (lane >> 3);

  const int start = (seg == 0)  ? 0  : reset_idx[seg - 1];
  const int end   = (seg == 32) ? TT : reset_idx[seg];
  if (start >= end) return;

  f32x2 wi2[4], wf2[4], wg2[4], wo2[4], wp2[4];
#pragma unroll
  for (int k = 0; k < 4; ++k) {
    wi2[k][0] = W_hh[(0  + j) * 8 + 2 * k]; wi2[k][1] = W_hh[(0  + j) * 8 + 2 * k + 1];
    wf2[k][0] = W_hh[(8  + j) * 8 + 2 * k]; wf2[k][1] = W_hh[(8  + j) * 8 + 2 * k + 1];
    wg2[k][0] = W_hh[(16 + j) * 8 + 2 * k]; wg2[k][1] = W_hh[(16 + j) * 8 + 2 * k + 1];
    wo2[k][0] = W_hh[(24 + j) * 8 + 2 * k]; wo2[k][1] = W_hh[(24 + j) * 8 + 2 * k + 1];
    wp2[k][0] = W_proj[2 * k];              wp2[k][1] = W_proj[2 * k + 1];
  }
  const float bp = b_proj[0];

  f32x2 h2[4] = {{0.f, 0.f}, {0.f, 0.f}, {0.f, 0.f}, {0.f, 0.f}};
  float c = 0.f;

  float* __restrict__ vout = out;                    // value   [T*B]
  float* __restrict__ hout = out + (size_t)TT * BB;  // rnn_out [T*B*8]

  const f32x4* __restrict__ xg4 = reinterpret_cast<const f32x4*>(xg);
  const size_t lbase = (size_t)b * 8 + j;            // + t*2048

  f32x4 bufA[8], bufB[8];

#define LOADC(buf, tc) do {                                                  \
  _Pragma("unroll")                                                          \
  for (int s = 0; s < 8; ++s) {                                              \
    int tt = (tc) + s; tt = tt < TT ? tt : TT - 1;   /* clamp: always valid */\
    (buf)[s] = __builtin_nontemporal_load(&xg4[(size_t)tt * 2048 + lbase]);  \
  }                                                                          \
} while (0)

// CHECKED: 1 -> per-step wave-uniform guard (tail); 0 -> branch-free body.
#define STEP8(buf, tc, CHECKED) do {                                         \
  _Pragma("unroll")                                                          \
  for (int s = 0; s < 8; ++s) {                                              \
    int t = (tc) + s;                                                        \
    if (!(CHECKED) || t < end) {                                             \
      f32x2 ai = {(buf)[s][0], 0.f}, af = {(buf)[s][1], 0.f};                \
      f32x2 ag = {(buf)[s][2], 0.f}, ao = {(buf)[s][3], 0.f};                \
      _Pragma("unroll")                                                      \
      for (int k = 0; k < 4; ++k) {                                          \
        ai += wi2[k] * h2[k];                                                \
        af += wf2[k] * h2[k];                                                \
        ag += wg2[k] * h2[k];                                                \
        ao += wo2[k] * h2[k];                                                \
      }                                                                      \
      float gi = ai[0] + ai[1], gf = af[0] + af[1];                          \
      float gg = ag[0] + ag[1], go = ao[0] + ao[1];                          \
      float si = sigm(gi), sf = sigm(gf), sg = tanh_fast(gg), so = sigm(go); \
      c = sf * c + si * sg;                                                  \
      float hj = so * tanh_fast(c);                                          \
      __builtin_nontemporal_store(hj, &hout[((size_t)t * BB + b) * 8 + j]);  \
      int hv = __float_as_int(hj);                                           \
      int r0 = __builtin_amdgcn_ds_swizzle(hv, 0x18);                        \
      int r1 = __builtin_amdgcn_ds_swizzle(hv, 0x38);                        \
      int r2 = __builtin_amdgcn_ds_swizzle(hv, 0x58);                        \
      int r3 = __builtin_amdgcn_ds_swizzle(hv, 0x78);                        \
      int r4 = __builtin_amdgcn_ds_swizzle(hv, 0x98);                        \
      int r5 = __builtin_amdgcn_ds_swizzle(hv, 0xB8);                        \
      int r6 = __builtin_amdgcn_ds_swizzle(hv, 0xD8);                        \
      int r7 = __builtin_amdgcn_ds_swizzle(hv, 0xF8);                        \
      h2[0][0] = __int_as_float(r0); h2[0][1] = __int_as_float(r1);          \
      h2[1][0] = __int_as_float(r2); h2[1][1] = __int_as_float(r3);          \
      h2[2][0] = __int_as_float(r4); h2[2][1] = __int_as_float(r5);          \
      h2[3][0] = __int_as_float(r6); h2[3][1] = __int_as_float(r7);          \
      f32x2 sv2 = wp2[0] * h2[0];                                            \
      sv2 += wp2[1] * h2[1];                                                 \
      sv2 += wp2[2] * h2[2];                                                 \
      sv2 += wp2[3] * h2[3];                                                 \
      float sv = bp + sv2[0] + sv2[1];                                       \
      if (j == 0) __builtin_nontemporal_store(sv, &vout[(size_t)t * BB + b]);\
    }                                                                        \
  }                                                                          \
} while (0)

  LOADC(bufA, start);
  LOADC(bufB, start + 8);
  int tc = start;
  // Fast path: whole 16-step window strictly inside the segment.
  for (; tc + 16 <= end; tc += 16) {
    STEP8(bufA, tc, 0);
    LOADC(bufA, tc + 16);      // ~8 steps ahead of use
    STEP8(bufB, tc + 8, 0);
    LOADC(bufB, tc + 24);
  }
  // Checked tail (0..15 remaining steps).
  if (tc < end) {
    STEP8(bufA, tc, 1);
    STEP8(bufB, tc + 8, 1);
  }
#undef LOADC
#undef STEP8
}

extern "C" void kernel_launch(void* const* d_in, const int* in_sizes, int n_in,
                              void* d_out, int out_size, void* d_ws, size_t ws_size,
                              hipStream_t stream) {
  const float* x      = (const float*)d_in[0];
  const int*   ridx   = (const int*)  d_in[1];
  const float* W_ih   = (const float*)d_in[2];
  const float* W_hh   = (const float*)d_in[3];
  const float* b_ih   = (const float*)d_in[4];
  const float* b_hh   = (const float*)d_in[5];
  const float* W_proj = (const float*)d_in[6];
  const float* b_proj = (const float*)d_in[7];
  float* out = (float*)d_out;

  float* xg  = (float*)d_ws;                          // T*B*32 f32 = 128 MiB
  char*  aux = (char*)d_ws + (size_t)134217728;       // after xg
  s16x8* whi = (s16x8*)aux;                           // 512 * 16 B = 8 KiB
  s16x8* wlo = whi + 512;                             // 8 KiB
  float* bo  = (float*)(wlo + 512);                   // 32 floats

  prep_kernel<<<1, 64, 0, stream>>>(W_ih, b_ih, b_hh, whi, wlo, bo);
  gates_kernel<<<(TT * BB) / 64, 256, 0, stream>>>(x, whi, wlo, bo, xg);
  rnn_kernel<<<dim3(33, 32), 64, 0, stream>>>(xg, ridx, W_hh, W_proj, b_proj, out);
}

// Round 15
// 243.227 us; speedup vs baseline: 1.0288x; 1.0288x over previous
//
#include <hip/hip_runtime.h>
#include <cstdint>

#define TT 4096
#define BB 256
#define ID 128

typedef float f32x4 __attribute__((ext_vector_type(4)));
typedef float f32x2 __attribute__((ext_vector_type(2)));
typedef short s16x8 __attribute__((ext_vector_type(8)));

__device__ __forceinline__ float rcp_fast(float x) { return __builtin_amdgcn_rcpf(x); }
__device__ __forceinline__ float sigm(float x) { return rcp_fast(1.0f + __expf(-x)); }
__device__ __forceinline__ float tanh_fast(float x) {
  float e = __expf(2.0f * x);          // large +x -> inf -> 1; large -x -> 0 -> -1
  return 1.0f - 2.0f * rcp_fast(e + 1.0f);
}

union U16B { uint32_t u[4]; s16x8 v; };

// Split 8 f32 into bf16-hi (truncate) + bf16-lo (exact residual, truncated).
// x = hi + rest exactly up to rest's own 2^-16; 3-product GEMM error ~1e-4.
__device__ __forceinline__ void split8(const float4 a, const float4 b,
                                       s16x8& hi, s16x8& lo) {
  uint32_t a0 = __float_as_uint(a.x), a1 = __float_as_uint(a.y);
  uint32_t a2 = __float_as_uint(a.z), a3 = __float_as_uint(a.w);
  uint32_t b0 = __float_as_uint(b.x), b1 = __float_as_uint(b.y);
  uint32_t b2 = __float_as_uint(b.z), b3 = __float_as_uint(b.w);
  U16B h;
  h.u[0] = (a0 >> 16) | (a1 & 0xffff0000u);
  h.u[1] = (a2 >> 16) | (a3 & 0xffff0000u);
  h.u[2] = (b0 >> 16) | (b1 & 0xffff0000u);
  h.u[3] = (b2 >> 16) | (b3 & 0xffff0000u);
  hi = h.v;
  float r0 = a.x - __uint_as_float(a0 & 0xffff0000u);
  float r1 = a.y - __uint_as_float(a1 & 0xffff0000u);
  float r2 = a.z - __uint_as_float(a2 & 0xffff0000u);
  float r3 = a.w - __uint_as_float(a3 & 0xffff0000u);
  float r4 = b.x - __uint_as_float(b0 & 0xffff0000u);
  float r5 = b.y - __uint_as_float(b1 & 0xffff0000u);
  float r6 = b.z - __uint_as_float(b2 & 0xffff0000u);
  float r7 = b.w - __uint_as_float(b3 & 0xffff0000u);
  U16B l;
  l.u[0] = (__float_as_uint(r0) >> 16) | (__float_as_uint(r1) & 0xffff0000u);
  l.u[1] = (__float_as_uint(r2) >> 16) | (__float_as_uint(r3) & 0xffff0000u);
  l.u[2] = (__float_as_uint(r4) >> 16) | (__float_as_uint(r5) & 0xffff0000u);
  l.u[3] = (__float_as_uint(r6) >> 16) | (__float_as_uint(r7) & 0xffff0000u);
  lo = l.v;
}

// One-time prep (R4-verified): split-bf16 B fragments in FINAL fragment order.
// Permuted-B mapping: output col m holds gate gp = (m&3)*8 + (m>>2)
// (xg layout [row][j][comp], comp = i,f,g,o). bo[m] = b_ih[gp]+b_hh[gp].
__global__ __launch_bounds__(64) void prep_kernel(
    const float* __restrict__ W_ih, const float* __restrict__ b_ih,
    const float* __restrict__ b_hh,
    s16x8* __restrict__ whi, s16x8* __restrict__ wlo, float* __restrict__ bo)
{
  const int lane = threadIdx.x;              // 0..63
  const int kq   = (lane >> 4) * 2;
  const float4* __restrict__ w4 = reinterpret_cast<const float4*>(W_ih);
#pragma unroll
  for (int kc = 0; kc < 4; ++kc) {
#pragma unroll
    for (int nf = 0; nf < 2; ++nf) {
      int m  = nf * 16 + (lane & 15);
      int gp = (m & 3) * 8 + (m >> 2);
      int q0 = kc * 8 + kq;
      float4 wa = w4[gp * 32 + q0];
      float4 wb = w4[gp * 32 + q0 + 1];
      s16x8 hi, lo;
      split8(wa, wb, hi, lo);
      whi[(kc * 2 + nf) * 64 + lane] = hi;
      wlo[(kc * 2 + nf) * 64 + lane] = lo;
    }
  }
  if (lane < 32) {
    int gp = (lane & 3) * 8 + (lane >> 2);
    bo[lane] = b_ih[gp] + b_hh[gp];
  }
}

// gates via MFMA (R4/R8-verified, byte-identical to the 244.0 µs config).
// BW-bound at ~4.6 TB/s effective mixed stream (measured via R9 probe);
// structural levers (occupancy, DMA pipeline, write-halving, NT) all null.
__global__ __launch_bounds__(256) void gates_kernel(
    const float* __restrict__ x,
    const s16x8* __restrict__ whi, const s16x8* __restrict__ wlo,
    const float* __restrict__ bo, float* __restrict__ xg)
{
  __shared__ float4 xt[64 * 32];   // 32 KB  [row][q ^ (row&31)]
  const int tid = threadIdx.x;
  const size_t row0 = (size_t)blockIdx.x * 64;

  const float4* __restrict__ src = reinterpret_cast<const float4*>(x) + row0 * 32;
#pragma unroll
  for (int it = 0; it < 8; ++it) {           // 2048 f4, coalesced
    int idx = it * 256 + tid;
    int r = idx >> 5, q = idx & 31;
    xt[r * 32 + (q ^ (r & 31))] = src[idx];
  }

  const int lane = tid & 63;
  const int wv   = tid >> 6;
  const int rloc = wv * 16 + (lane & 15);    // A-frag row (local)
  const int kq   = (lane >> 4) * 2;          // quad offset of this lane's k-chunk

  s16x8 Bh[4][2], Bl[4][2];
#pragma unroll
  for (int kc = 0; kc < 4; ++kc) {
#pragma unroll
    for (int nf = 0; nf < 2; ++nf) {
      Bh[kc][nf] = whi[(kc * 2 + nf) * 64 + lane];
      Bl[kc][nf] = wlo[(kc * 2 + nf) * 64 + lane];
    }
  }
  const float bo0 = bo[lane & 15];
  const float bo1 = bo[16 + (lane & 15)];

  __syncthreads();

  f32x4 acc[2] = {{0.f, 0.f, 0.f, 0.f}, {0.f, 0.f, 0.f, 0.f}};
#pragma unroll
  for (int kc = 0; kc < 4; ++kc) {
    int q0 = kc * 8 + kq;
    float4 xa = xt[rloc * 32 + (q0 ^ (rloc & 31))];
    float4 xb = xt[rloc * 32 + ((q0 + 1) ^ (rloc & 31))];
    s16x8 Ah, Al;
    split8(xa, xb, Ah, Al);
#pragma unroll
    for (int nf = 0; nf < 2; ++nf) {
      acc[nf] = __builtin_amdgcn_mfma_f32_16x16x32_bf16(Ah, Bh[kc][nf], acc[nf], 0, 0, 0);
      acc[nf] = __builtin_amdgcn_mfma_f32_16x16x32_bf16(Ah, Bl[kc][nf], acc[nf], 0, 0, 0);
      acc[nf] = __builtin_amdgcn_mfma_f32_16x16x32_bf16(Al, Bh[kc][nf], acc[nf], 0, 0, 0);
    }
  }

  // C/D: col = lane&15, row = (lane>>4)*4 + reg  [m89-verified]
#pragma unroll
  for (int nf = 0; nf < 2; ++nf) {
    int m = nf * 16 + (lane & 15);
    float b = nf ? bo1 : bo0;
    size_t rowg = row0 + wv * 16 + (lane >> 4) * 4;
#pragma unroll
    for (int reg = 0; reg < 4; ++reg) {
      xg[(rowg + reg) * 32 + m] = acc[nf][reg] + b;
    }
  }
}

// rnn (R8-verified, byte-identical to the 244.0 µs config): 1-wave blocks,
// grid (33 segments, 32 batch-chunks of 8). Latency-bound on the longest
// reset segment (~505 steps x ~440 cyc serial chain = ~93 µs, measured via
// R9 double-launch probe). ds_swizzle h-broadcast + packed f32x2 dots.
__global__ __launch_bounds__(64) void rnn_kernel(
    const float* __restrict__ xg, const int* __restrict__ reset_idx,
    const float* __restrict__ W_hh, const float* __restrict__ W_proj,
    const float* __restrict__ b_proj, float* __restrict__ out)
{
  const int seg  = blockIdx.x;          // 0..32
  const int lane = threadIdx.x;
  const int j    = lane & 7;
  const int b    = blockIdx.y * 8 + (lane >> 3);

  const int start = (seg == 0)  ? 0  : reset_idx[seg - 1];
  const int end   = (seg == 32) ? TT : reset_idx[seg];
  if (start >= end) return;

  f32x2 wi2[4], wf2[4], wg2[4], wo2[4], wp2[4];
#pragma unroll
  for (int k = 0; k < 4; ++k) {
    wi2[k][0] = W_hh[(0  + j) * 8 + 2 * k]; wi2[k][1] = W_hh[(0  + j) * 8 + 2 * k + 1];
    wf2[k][0] = W_hh[(8  + j) * 8 + 2 * k]; wf2[k][1] = W_hh[(8  + j) * 8 + 2 * k + 1];
    wg2[k][0] = W_hh[(16 + j) * 8 + 2 * k]; wg2[k][1] = W_hh[(16 + j) * 8 + 2 * k + 1];
    wo2[k][0] = W_hh[(24 + j) * 8 + 2 * k]; wo2[k][1] = W_hh[(24 + j) * 8 + 2 * k + 1];
    wp2[k][0] = W_proj[2 * k];              wp2[k][1] = W_proj[2 * k + 1];
  }
  const float bp = b_proj[0];

  f32x2 h2[4] = {{0.f, 0.f}, {0.f, 0.f}, {0.f, 0.f}, {0.f, 0.f}};
  float c = 0.f;

  float* __restrict__ vout = out;                    // value   [T*B]
  float* __restrict__ hout = out + (size_t)TT * BB;  // rnn_out [T*B*8]

  const float4* __restrict__ xg4 = reinterpret_cast<const float4*>(xg);
  const size_t lbase = (size_t)b * 8 + j;            // + t*2048

  float4 bufA[8], bufB[8];

#define LOADC(buf, tc) do {                                                  \
  _Pragma("unroll")                                                          \
  for (int s = 0; s < 8; ++s) {                                              \
    int tt = (tc) + s; tt = tt < TT ? tt : TT - 1;   /* clamp: always valid */\
    (buf)[s] = xg4[(size_t)tt * 2048 + lbase];                               \
  }                                                                          \
} while (0)

#define STEP8(buf, tc) do {                                                  \
  _Pragma("unroll")                                                          \
  for (int s = 0; s < 8; ++s) {                                              \
    int t = (tc) + s;                                                        \
    if (t < end) {       /* wave-uniform branch */                           \
      f32x2 ai = {(buf)[s].x, 0.f}, af = {(buf)[s].y, 0.f};                  \
      f32x2 ag = {(buf)[s].z, 0.f}, ao = {(buf)[s].w, 0.f};                  \
      _Pragma("unroll")                                                      \
      for (int k = 0; k < 4; ++k) {                                          \
        ai += wi2[k] * h2[k];                                                \
        af += wf2[k] * h2[k];                                                \
        ag += wg2[k] * h2[k];                                                \
        ao += wo2[k] * h2[k];                                                \
      }                                                                      \
      float gi = ai[0] + ai[1], gf = af[0] + af[1];                          \
      float gg = ag[0] + ag[1], go = ao[0] + ao[1];                          \
      float si = sigm(gi), sf = sigm(gf), sg = tanh_fast(gg), so = sigm(go); \
      c = sf * c + si * sg;                                                  \
      float hj = so * tanh_fast(c);                                          \
      hout[((size_t)t * BB + b) * 8 + j] = hj;                               \
      int hv = __float_as_int(hj);                                           \
      int r0 = __builtin_amdgcn_ds_swizzle(hv, 0x18);                        \
      int r1 = __builtin_amdgcn_ds_swizzle(hv, 0x38);                        \
      int r2 = __builtin_amdgcn_ds_swizzle(hv, 0x58);                        \
      int r3 = __builtin_amdgcn_ds_swizzle(hv, 0x78);                        \
      int r4 = __builtin_amdgcn_ds_swizzle(hv, 0x98);                        \
      int r5 = __builtin_amdgcn_ds_swizzle(hv, 0xB8);                        \
      int r6 = __builtin_amdgcn_ds_swizzle(hv, 0xD8);                        \
      int r7 = __builtin_amdgcn_ds_swizzle(hv, 0xF8);                        \
      h2[0][0] = __int_as_float(r0); h2[0][1] = __int_as_float(r1);          \
      h2[1][0] = __int_as_float(r2); h2[1][1] = __int_as_float(r3);          \
      h2[2][0] = __int_as_float(r4); h2[2][1] = __int_as_float(r5);          \
      h2[3][0] = __int_as_float(r6); h2[3][1] = __int_as_float(r7);          \
      f32x2 sv2 = wp2[0] * h2[0];                                            \
      sv2 += wp2[1] * h2[1];                                                 \
      sv2 += wp2[2] * h2[2];                                                 \
      sv2 += wp2[3] * h2[3];                                                 \
      float sv = bp + sv2[0] + sv2[1];                                       \
      if (j == 0) vout[(size_t)t * BB + b] = sv;                             \
    }                                                                        \
  }                                                                          \
} while (0)

  LOADC(bufA, start);
  LOADC(bufB, start + 8);
  for (int tc = start; tc < end; tc += 16) {
    STEP8(bufA, tc);
    LOADC(bufA, tc + 16);      // ~8 steps ahead of use
    STEP8(bufB, tc + 8);
    LOADC(bufB, tc + 24);
  }
#undef LOADC
#undef STEP8
}

extern "C" void kernel_launch(void* const* d_in, const int* in_sizes, int n_in,
                              void* d_out, int out_size, void* d_ws, size_t ws_size,
                              hipStream_t stream) {
  const float* x      = (const float*)d_in[0];
  const int*   ridx   = (const int*)  d_in[1];
  const float* W_ih   = (const float*)d_in[2];
  const float* W_hh   = (const float*)d_in[3];
  const float* b_ih   = (const float*)d_in[4];
  const float* b_hh   = (const float*)d_in[5];
  const float* W_proj = (const float*)d_in[6];
  const float* b_proj = (const float*)d_in[7];
  float* out = (float*)d_out;

  float* xg  = (float*)d_ws;                          // T*B*32 f32 = 128 MiB
  char*  aux = (char*)d_ws + (size_t)134217728;       // after xg
  s16x8* whi = (s16x8*)aux;                           // 512 * 16 B = 8 KiB
  s16x8* wlo = whi + 512;                             // 8 KiB
  float* bo  = (float*)(wlo + 512);                   // 32 floats

  prep_kernel<<<1, 64, 0, stream>>>(W_ih, b_ih, b_hh, whi, wlo, bo);
  gates_kernel<<<(TT * BB) / 64, 256, 0, stream>>>(x, whi, wlo, bo, xg);
  rnn_kernel<<<dim3(33, 32), 64, 0, stream>>>(xg, ridx, W_hh, W_proj, b_proj, out);
}